// Round 9
// baseline (232.029 us; speedup 1.0000x reference)
//
#include <hip/hip_runtime.h>
#include <hip/hip_bf16.h>
#include <math.h>

#define BATCH 4
#define N 2048
#define D 256
#define NH 4
#define DH 64
#define TOPK 9
#define NEG_BIG -1e30f

typedef __bf16 bf16;
typedef __bf16 bf16x4 __attribute__((ext_vector_type(4)));
typedef __bf16 bf16x8 __attribute__((ext_vector_type(8)));
typedef float f32x4 __attribute__((ext_vector_type(4)));

#define PK3(a,b,c) ((a) | ((b) << 2) | ((c) << 4))
#define PK6(a,b,c,d,e,f) ((a) | ((b) << 2) | ((c) << 4) | ((d) << 6) | ((e) << 8) | ((f) << 10))

// s_waitcnt with ONLY vmcnt=N. gfx9 encoding: vmcnt[3:0]@0, expcnt@4,
// lgkmcnt@8, vmcnt[5:4]@14.
#define WAITVM(Nc) __builtin_amdgcn_s_waitcnt((((Nc) & 0xf)) | (7u << 4) | (0xfu << 8) | ((((unsigned)(Nc)) >> 4) << 14))

__device__ __forceinline__ void async_cp16(const bf16* g, const bf16* l) {
  __builtin_amdgcn_global_load_lds(
      (const __attribute__((address_space(1))) void*)(uintptr_t)g,
      (__attribute__((address_space(3))) void*)(uintptr_t)l, 16, 0, 0);
}

// ---------------------------------------------------------------------------
// prep: blk<8192: x -> XsN (L2-norm, 2-way split h/m, stride 512) + norms
//       blk<8256: W{q,k,v,o} -> Wt via coalesced 64x64 LDS transpose
//       else (128 blks): zero the 2 MB adjacency mask
// ---------------------------------------------------------------------------
__global__ __launch_bounds__(64) void prep_kernel(const float* __restrict__ x,
                                                  const float* __restrict__ Wq,
                                                  const float* __restrict__ Wk,
                                                  const float* __restrict__ Wv,
                                                  const float* __restrict__ Wo,
                                                  bf16* __restrict__ XsN,
                                                  bf16* __restrict__ Wt,
                                                  float* __restrict__ norms,
                                                  uint4* __restrict__ mask4) {
  __shared__ float T[64][65];
  int blk = blockIdx.x;
  int lane = threadIdx.x;
  if (blk < 8192) {
    float4 v = *(const float4*)(x + (size_t)blk * D + lane * 4);
    float ss = v.x * v.x + v.y * v.y + v.z * v.z + v.w * v.w;
    for (int off = 32; off; off >>= 1) ss += __shfl_down(ss, off);
    ss = __shfl(ss, 0);
    float nrm = fmaxf(sqrtf(ss), 1e-12f);
    if (lane == 0) norms[blk] = nrm;
    float sc = 1.0f / nrm;
    float xs[4] = {v.x * sc, v.y * sc, v.z * sc, v.w * sc};
    bf16* o = XsN + (size_t)blk * 512 + lane * 4;
#pragma unroll
    for (int j = 0; j < 4; ++j) {
      float xv = xs[j];
      bf16 h = (bf16)xv;
      o[j] = h;
      o[256 + j] = (bf16)(xv - (float)h);
    }
  } else if (blk < 8256) {
    int tj = blk - 8192;            // 0..63: 4 W x 16 (64x64) tiles
    int wsel = tj >> 4;
    int tile = tj & 15;
    int tr = (tile >> 2) * 64;      // k range
    int tc = (tile & 3) * 64;       // j range
    const float* W = (wsel == 0) ? Wq : (wsel == 1) ? Wk : (wsel == 2) ? Wv : Wo;
    int l4 = lane & 15, lr = lane >> 4;
#pragma unroll
    for (int it = 0; it < 16; ++it) {
      int k = tr + it * 4 + lr;
      float4 w4 = *(const float4*)(W + (size_t)k * D + tc + l4 * 4);
      T[l4 * 4 + 0][it * 4 + lr] = w4.x;   // T[j'][k'] = W[tr+k'][tc+j']
      T[l4 * 4 + 1][it * 4 + lr] = w4.y;
      T[l4 * 4 + 2][it * 4 + lr] = w4.z;
      T[l4 * 4 + 3][it * 4 + lr] = w4.w;
    }
    __syncthreads();
    int jj = wsel * 256 + tc + lane;
    bf16* dst = Wt + (size_t)jj * 512 + tr;
#pragma unroll
    for (int c = 0; c < 8; ++c) {
      bf16x8 hv, mv;
#pragma unroll
      for (int t = 0; t < 8; ++t) {
        float w = T[lane][c * 8 + t];
        bf16 h = (bf16)w;
        hv[t] = h;
        mv[t] = (bf16)(w - (float)h);
      }
      *(bf16x8*)(dst + c * 8) = hv;
      *(bf16x8*)(dst + 256 + c * 8) = mv;
    }
  } else {
    int base = (blk - 8256) * 1024 + lane;
#pragma unroll
    for (int t = 0; t < 16; ++t)
      mask4[base + t * 64] = make_uint4(0, 0, 0, 0);
  }
}

// ---------------------------------------------------------------------------
// 128x256 4-wave GEMM core (round 5 PROVEN: 43us).  BK=32, counted WAITVM(6),
// swizzle (r>>1)&3, 2 blk/CU.
// outmode 1: fp32 nontemporal + optional mirror (f32x4 vector store).
// outmode 2: bf16 with per-row norm rescale (qkv).
// ---------------------------------------------------------------------------
__device__ __forceinline__ void gemm_core128x256(bf16* As, bf16* Bs,
                                                 const bf16* __restrict__ Ab,
                                                 const bf16* __restrict__ Bb,
                                                 void* __restrict__ Cvoid,
                                                 int ldc, int nsteps,
                                                 int amap, int bmap,
                                                 int row0, int col0,
                                                 int outmode, bool mirror,
                                                 const float* __restrict__ rowscale) {
  int tid = threadIdx.x;
  int lane = tid & 63;
  int wv = tid >> 6;            // 4 waves: 2M x 2N
  int wm = (wv >> 1) * 64;      // wave rows: 64 of 128
  int wn = (wv & 1) * 128;      // wave cols: 128 of 256
  int fr = lane & 15;
  int G = lane >> 4;            // k-slot 0..3 (8 bf16 each)

  f32x4 acc[4][8] = {};

  auto issue = [&](int st, int buf) {
    int ch = st >> 3;                                        // 256-K chunk
    int aoff = (((amap >> (ch * 2)) & 3) << 8) | ((st & 7) << 5);
    int boff = (((bmap >> (ch * 2)) & 3) << 8) | ((st & 7) << 5);
    // A: 128x32 = 512 16B-slots, 2/thread
#pragma unroll
    for (int q = 0; q < 2; ++q) {
      int s = q * 256 + tid;
      int r = s >> 2, sl = s & 3;
      async_cp16(Ab + (size_t)r * 512 + ((sl ^ ((r >> 1) & 3)) << 3) + aoff,
                 &As[buf * 4096 + s * 8]);
    }
    // B: 256x32 = 1024 16B-slots, 4/thread
#pragma unroll
    for (int q = 0; q < 4; ++q) {
      int s = q * 256 + tid;
      int r = s >> 2, sl = s & 3;
      async_cp16(Bb + (size_t)r * 512 + ((sl ^ ((r >> 1) & 3)) << 3) + boff,
                 &Bs[buf * 8192 + s * 8]);
    }
  };

  issue(0, 0);
  for (int st = 0; st < nsteps; ++st) {
    int buf = st & 1;
    if (st + 1 < nsteps) {
      issue(st + 1, buf ^ 1);
      WAITVM(6);        // exactly the 6 just-issued outstanding; tile st landed
    } else {
      WAITVM(0);
    }
    __builtin_amdgcn_s_barrier();
    bf16x8 af[4], bfr[8];
#pragma unroll
    for (int mi = 0; mi < 4; ++mi) {
      int r = wm + mi * 16 + fr;
      af[mi] = *(const bf16x8*)&As[buf * 4096 + r * 32 + ((G ^ ((r >> 1) & 3)) << 3)];
    }
#pragma unroll
    for (int nj = 0; nj < 8; ++nj) {
      int r = wn + nj * 16 + fr;
      bfr[nj] = *(const bf16x8*)&Bs[buf * 8192 + r * 32 + ((G ^ ((r >> 1) & 3)) << 3)];
    }
    __builtin_amdgcn_s_setprio(1);
#pragma unroll
    for (int mi = 0; mi < 4; ++mi)
#pragma unroll
      for (int nj = 0; nj < 8; ++nj)
        acc[mi][nj] = __builtin_amdgcn_mfma_f32_16x16x32_bf16(af[mi], bfr[nj], acc[mi][nj], 0, 0, 0);
    __builtin_amdgcn_s_setprio(0);
    __builtin_amdgcn_s_barrier();
  }

  int er = (lane >> 4) * 4;
  int ec = lane & 15;
#pragma unroll
  for (int mi = 0; mi < 4; ++mi) {
    int rb = row0 + wm + mi * 16 + er;
    float scl[4] = {1.f, 1.f, 1.f, 1.f};
    if (rowscale) {
      float4 s4 = *(const float4*)(rowscale + rb);
      scl[0] = s4.x; scl[1] = s4.y; scl[2] = s4.z; scl[3] = s4.w;
    }
#pragma unroll
    for (int nj = 0; nj < 8; ++nj) {
      int cb = col0 + wn + nj * 16 + ec;
      if (outmode == 1) {
        float* Cb = (float*)Cvoid;
#pragma unroll
        for (int reg = 0; reg < 4; ++reg)
          __builtin_nontemporal_store(acc[mi][nj][reg],
                                      &Cb[(size_t)(rb + reg) * ldc + cb]);
        if (mirror) {
          // mirrored: 4 consecutive rows -> contiguous col-major addresses
          __builtin_nontemporal_store(acc[mi][nj],
                                      (f32x4*)&Cb[(size_t)cb * ldc + rb]);
        }
      } else {
        bf16* Cb = (bf16*)Cvoid;
#pragma unroll
        for (int reg = 0; reg < 4; ++reg)
          Cb[(size_t)(rb + reg) * ldc + cb] = (bf16)(acc[mi][nj][reg] * scl[reg]);
      }
    }
  }
}

// fused sim + qkv, 128x256 tiles: 288 sim (24-step) + 192 qkv (16-step).
// SSQSQ dispatch interleave (round 8) — each CU's 2 resident blocks average
// ~40 steps.  Decode unchanged.
__global__ __launch_bounds__(256, 2) void gemm_fused128x256_kernel(
    const bf16* __restrict__ XsN, float* __restrict__ sim,
    int amap_s, int bmap_s,
    const bf16* __restrict__ Wt, bf16* __restrict__ qkv,
    int amap_q, int bmap_q, const float* __restrict__ norms) {
  __shared__ bf16 As[2 * 128 * 32];   // 16 KB
  __shared__ bf16 Bs[2 * 256 * 32];   // 32 KB
  int g = blockIdx.x;                 // 0..479 = 5 * 96
  int rr = g % 5, u = g / 5;
  if (rr == 0 || rr == 1 || rr == 3) {
    int s = u * 3 + (rr == 3 ? 2 : rr);  // 0..287
    int xcd = s & 7;
    int z = xcd >> 1;
    int t = (xcd & 1) * 36 + (s >> 3);   // 0..71 within batch
    int half = t & 1;
    int uu = t >> 1;                     // supertile 0..35
    int by = 0;
    while (uu >= 8 - by) { uu -= 8 - by; ++by; }
    int bx = by + uu;
    int row0 = by * 256 + half * 128;
    int col0 = bx * 256;
    gemm_core128x256(As, Bs,
                     XsN + (size_t)z * N * 512 + (size_t)row0 * 512,
                     XsN + (size_t)z * N * 512 + (size_t)col0 * 512,
                     sim + (size_t)z * N * N,
                     N, 24, amap_s, bmap_s, row0, col0,
                     1, bx != by, nullptr);
  } else {
    int q = u * 2 + (rr == 4 ? 1 : 0);   // 0..191
    int xcd = q & 7;
    int slot = q >> 3;                   // 0..23
    int z = xcd >> 1;
    int by = z * 16 + (xcd & 1) * 8 + slot / 3;  // 0..63 global 128-row tiles
    int bx = slot % 3;
    gemm_core128x256(As, Bs,
                     XsN + (size_t)by * 128 * 512,
                     Wt + (size_t)bx * 256 * 512,
                     qkv, 768, 16, amap_q, bmap_q,
                     by * 128, bx * 256, 2, false, norms);
  }
}

// ---------------------------------------------------------------------------
// 128^2 GEMM core — small-ws fallback.
// ---------------------------------------------------------------------------
__device__ __forceinline__ void gemm_core(bf16* As, bf16* Bs,
                                          const bf16* __restrict__ Ab,
                                          const bf16* __restrict__ Bb,
                                          void* __restrict__ Cvoid,
                                          int lda, int ldb, int ldc,
                                          int nsteps, int amap, int bmap,
                                          int row0, int col0,
                                          int outmode, bool mirror,
                                          const float* __restrict__ rowscale) {
  int tid = threadIdx.x;
  int lane = tid & 63;
  int wv = tid >> 6;
  int wm = (wv >> 1) * 64;
  int wn = (wv & 1) * 64;

  int rbase = tid >> 2;
  int gperm = (tid & 3) ^ ((rbase >> 1) & 3);
  const bf16* ga0 = Ab + (size_t)rbase * lda + gperm * 8;
  const bf16* gb0 = Bb + (size_t)rbase * ldb + gperm * 8;
  int ldsoff = tid * 8;

  int fr = lane & 15;
  int G = lane >> 4;

  f32x4 acc[4][4] = {};

  auto issue = [&](int st, int buf) {
    int ch = st >> 3;
    int aoff = (((amap >> (ch * 2)) & 3) << 8) | ((st & 7) << 5);
    int boff = (((bmap >> (ch * 2)) & 3) << 8) | ((st & 7) << 5);
#pragma unroll
    for (int q = 0; q < 2; ++q)
      async_cp16(ga0 + (size_t)q * 64 * lda + aoff, &As[buf * 4096 + ldsoff + q * 2048]);
#pragma unroll
    for (int q = 0; q < 2; ++q)
      async_cp16(gb0 + (size_t)q * 64 * ldb + boff, &Bs[buf * 4096 + ldsoff + q * 2048]);
  };

  issue(0, 0);
  for (int st = 0; st < nsteps; ++st) {
    int buf = st & 1;
    if (st + 1 < nsteps) {
      issue(st + 1, buf ^ 1);
      WAITVM(4);
    } else {
      WAITVM(0);
    }
    __builtin_amdgcn_s_barrier();
    bf16x8 af[4], bfr[4];
#pragma unroll
    for (int mi = 0; mi < 4; ++mi) {
      int r = wm + mi * 16 + fr;
      af[mi] = *(const bf16x8*)&As[buf * 4096 + r * 32 + ((G ^ ((r >> 1) & 3)) << 3)];
    }
#pragma unroll
    for (int nj = 0; nj < 4; ++nj) {
      int r = wn + nj * 16 + fr;
      bfr[nj] = *(const bf16x8*)&Bs[buf * 4096 + r * 32 + ((G ^ ((r >> 1) & 3)) << 3)];
    }
#pragma unroll
    for (int mi = 0; mi < 4; ++mi)
#pragma unroll
      for (int nj = 0; nj < 4; ++nj)
        acc[mi][nj] = __builtin_amdgcn_mfma_f32_16x16x32_bf16(af[mi], bfr[nj], acc[mi][nj], 0, 0, 0);
    __builtin_amdgcn_s_barrier();
  }

  int er = (lane >> 4) * 4;
  int ec = lane & 15;
#pragma unroll
  for (int mi = 0; mi < 4; ++mi) {
    int rb = row0 + wm + mi * 16 + er;
    float scl[4] = {1.f, 1.f, 1.f, 1.f};
    if (rowscale) {
      float4 s4 = *(const float4*)(rowscale + rb);
      scl[0] = s4.x; scl[1] = s4.y; scl[2] = s4.z; scl[3] = s4.w;
    }
#pragma unroll
    for (int nj = 0; nj < 4; ++nj) {
      int cb = col0 + wn + nj * 16 + ec;
      if (outmode == 1) {
        float* Cb = (float*)Cvoid;
#pragma unroll
        for (int reg = 0; reg < 4; ++reg)
          __builtin_nontemporal_store(acc[mi][nj][reg],
                                      &Cb[(size_t)(rb + reg) * ldc + cb]);
        if (mirror) {
#pragma unroll
          for (int reg = 0; reg < 4; ++reg)
            __builtin_nontemporal_store(acc[mi][nj][reg],
                                        &Cb[(size_t)cb * ldc + rb + reg]);
        }
      } else {
        bf16* Cb = (bf16*)Cvoid;
#pragma unroll
        for (int reg = 0; reg < 4; ++reg)
          Cb[(size_t)(rb + reg) * ldc + cb] = (bf16)(acc[mi][nj][reg] * scl[reg]);
      }
    }
  }
}

// sim-only dispatch (small-ws fallback): grid (544)
__global__ __launch_bounds__(256, 4) void gemm_sim_kernel(const bf16* __restrict__ XsN,
                                                          float* __restrict__ sim,
                                                          int amap, int bmap) {
  __shared__ bf16 As[2 * 128 * 32];
  __shared__ bf16 Bs[2 * 128 * 32];
  int g = blockIdx.x;
  int xcd = g & 7;
  int slot = g >> 3;
  int z = xcd >> 1;
  int t = (xcd & 1) * 68 + slot;
  int by = 0;
  while (t >= 16 - by) { t -= 16 - by; ++by; }
  int bx = by + t;
  gemm_core(As, Bs,
            XsN + (size_t)z * N * 512 + (size_t)by * 128 * 512,
            XsN + (size_t)z * N * 512 + (size_t)bx * 128 * 512,
            sim + (size_t)z * N * N,
            512, 512, N, 24, amap, bmap, by * 128, bx * 128,
            1, bx != by, nullptr);
}

// generic qkv dispatch (small-ws fallback): grid (6, 64), bf16 out
__global__ __launch_bounds__(256, 4) void gemm_qkv_kernel(const bf16* __restrict__ XsN,
                                                          const bf16* __restrict__ Wt,
                                                          bf16* __restrict__ qkv,
                                                          int amap, int bmap,
                                                          const float* __restrict__ norms) {
  __shared__ bf16 As[2 * 128 * 32];
  __shared__ bf16 Bs[2 * 128 * 32];
  gemm_core(As, Bs,
            XsN + (size_t)blockIdx.y * 128 * 512,
            Wt + (size_t)blockIdx.x * 128 * 512,
            qkv, 512, 512, 768, 16, amap, bmap,
            blockIdx.y * 128, blockIdx.x * 128, 2, false, norms);
}

// ---------------------------------------------------------------------------
// top-9 per row, round 9: ONE row per wave (round-8's 2-row version spilled:
// VGPR_Count=48 < 64 floats needed -> scratch traffic, 44us).  4 waves/block,
// grid 2048.  The serial masked 32-scan (31-deep dependent cmp/sel chain) is
// replaced by a 5-level tournament tree (leaf-masked, lower-index wins ties)
// — identical selection set, dependency depth 31->5.
// ---------------------------------------------------------------------------
__global__ __launch_bounds__(256) void topk_adj_kernel(const float* __restrict__ sim,
                                                       unsigned* __restrict__ mask) {
  int wv = threadIdx.x >> 6;
  int lane = threadIdx.x & 63;
  int row = blockIdx.x * 4 + wv;
  int b = row >> 11, r = row & 2047;
  const float* srow = sim + (size_t)row * N;
  float v[32];
#pragma unroll
  for (int it = 0; it < 8; ++it) {
    float4 q = *(const float4*)(srow + it * 256 + lane * 4);
    v[it * 4 + 0] = q.x; v[it * 4 + 1] = q.y;
    v[it * 4 + 2] = q.z; v[it * 4 + 3] = q.w;
  }
  unsigned removed = 0;
  for (int rs = 0; rs < TOPK; ++rs) {
    // 5-level tournament tree; tie -> lower local i (== lower global idx
    // within a lane, since gidx is monotone in i for fixed lane).
    float tv[16]; int ti[16];
#pragma unroll
    for (int j = 0; j < 16; ++j) {
      float a = ((removed >> (2 * j)) & 1u) ? -3e38f : v[2 * j];
      float bq = ((removed >> (2 * j + 1)) & 1u) ? -3e38f : v[2 * j + 1];
      bool t = bq > a;
      tv[j] = t ? bq : a;
      ti[j] = t ? 2 * j + 1 : 2 * j;
    }
#pragma unroll
    for (int w = 8; w >= 1; w >>= 1)
#pragma unroll
      for (int j = 0; j < 8; ++j)
        if (j < w) {
          bool t = tv[j + w] > tv[j];
          tv[j] = t ? tv[j + w] : tv[j];
          ti[j] = t ? ti[j + w] : ti[j];
        }
    float m = tv[0];
    int mi = ti[0];
    int gidx = ((mi >> 2) << 8) + lane * 4 + (mi & 3);
    for (int off = 32; off; off >>= 1) {
      float om = __shfl_down(m, off);
      int og = __shfl_down(gidx, off);
      if (om > m || (om == m && og < gidx)) { m = om; gidx = og; }
    }
    gidx = __shfl(gidx, 0);
    if (((gidx >> 2) & 63) == lane)
      removed |= 1u << (((gidx >> 8) << 2) | (gidx & 3));
    if (lane == 0) {
      atomicOr(&mask[(size_t)row * 64 + (gidx >> 5)], 1u << (gidx & 31));
      atomicOr(&mask[(((size_t)b << 11) + gidx) * 64 + (r >> 5)], 1u << (r & 31));
    }
  }
}

// ---------------------------------------------------------------------------
// sparse attention: 4 waves/block, one (b,n) row per wave; XCD-aware decode.
// PV relayout (round 7): lane l owns dims (l&15)*4..+3 of head l>>4; one
// bf16x4 V load per neighbor.  Accumulation order per (h,d) unchanged.
// ---------------------------------------------------------------------------
__global__ __launch_bounds__(256) void attn_kernel(const bf16* __restrict__ qkv,
                                                   const unsigned* __restrict__ mask,
                                                   bf16* __restrict__ aos) {
  __shared__ float sq[4][256];
  __shared__ unsigned short nbr[4][2048];
  __shared__ int s_nn[4];
  int wv = threadIdx.x >> 6;
  int lane = threadIdx.x & 63;
  int hl = lane >> 4;                 // my head for PV/output
  int g = blockIdx.x;
  int xcd = g & 7;
  int b = xcd >> 1;
  int tile = (xcd & 1) * 256 + (g >> 3);
  int bn = b * N + tile * 4 + wv;
  if (lane == 0) s_nn[wv] = 0;
  {
    bf16x4 qv = *(const bf16x4*)(qkv + (size_t)bn * 768 + lane * 4);
#pragma unroll
    for (int j = 0; j < 4; ++j) sq[wv][lane * 4 + j] = (float)qv[j];
  }
  __syncthreads();
  unsigned bits = mask[(size_t)bn * (N / 32) + lane];
  while (bits) {
    int bit = __ffs(bits) - 1;
    bits &= bits - 1;
    int p = atomicAdd(&s_nn[wv], 1);
    nbr[wv][p] = (unsigned short)(lane * 32 + bit);
  }
  __syncthreads();
  int nn = s_nn[wv];
  const bf16* base = qkv + (size_t)b * N * 768;
  float acc2[4] = {0.f, 0.f, 0.f, 0.f};   // dims (lane&15)*4+{0..3} of head hl

  auto score4 = [&](int j, float* s) {
    const bf16* kr = base + (size_t)j * 768 + 256;
#pragma unroll
    for (int h = 0; h < 4; ++h) {
      float a = 0.f;
#pragma unroll
      for (int c = 0; c < DH; c += 8) {
        bf16x8 kk = *(const bf16x8*)(kr + h * DH + c);
#pragma unroll
        for (int t = 0; t < 8; ++t) a += sq[wv][h * DH + c + t] * (float)kk[t];
      }
      s[h] = a * 0.125f;
    }
  };

  if (nn <= 64) {
    float s[4] = {NEG_BIG, NEG_BIG, NEG_BIG, NEG_BIG};
    if (lane < nn) score4(nbr[wv][lane], s);
    float w[4], l[4];
#pragma unroll
    for (int h = 0; h < 4; ++h) {
      float m = s[h];
      for (int off = 32; off; off >>= 1) m = fmaxf(m, __shfl_down(m, off));
      m = __shfl(m, 0);
      float e = (lane < nn) ? __expf(s[h] - m) : 0.f;
      float ls = e;
      for (int off = 32; off; off >>= 1) ls += __shfl_down(ls, off);
      l[h] = __shfl(ls, 0);
      w[h] = e;
    }
    auto pickw = [&](int ii) {
      float a0 = __shfl(w[0], ii), a1 = __shfl(w[1], ii);
      float a2 = __shfl(w[2], ii), a3 = __shfl(w[3], ii);
      return hl == 0 ? a0 : (hl == 1 ? a1 : (hl == 2 ? a2 : a3));
    };
    int i = 0;
    for (; i + 4 <= nn; i += 4) {
      int j0 = nbr[wv][i + 0], j1 = nbr[wv][i + 1];
      int j2 = nbr[wv][i + 2], j3 = nbr[wv][i + 3];
      bf16x4 v0 = *(const bf16x4*)(base + (size_t)j0 * 768 + 512 + lane * 4);
      bf16x4 v1 = *(const bf16x4*)(base + (size_t)j1 * 768 + 512 + lane * 4);
      bf16x4 v2 = *(const bf16x4*)(base + (size_t)j2 * 768 + 512 + lane * 4);
      bf16x4 v3 = *(const bf16x4*)(base + (size_t)j3 * 768 + 512 + lane * 4);
      float w0 = pickw(i + 0), w1 = pickw(i + 1);
      float w2 = pickw(i + 2), w3 = pickw(i + 3);
#pragma unroll
      for (int t = 0; t < 4; ++t)
        acc2[t] += w0 * (float)v0[t] + w1 * (float)v1[t] +
                   w2 * (float)v2[t] + w3 * (float)v3[t];
    }
    for (; i < nn; ++i) {
      bf16x4 v0 = *(const bf16x4*)(base + (size_t)nbr[wv][i] * 768 + 512 + lane * 4);
      float w0 = pickw(i);
#pragma unroll
      for (int t = 0; t < 4; ++t) acc2[t] += w0 * (float)v0[t];
    }
    float ldiv = hl == 0 ? l[0] : (hl == 1 ? l[1] : (hl == 2 ? l[2] : l[3]));
#pragma unroll
    for (int t = 0; t < 4; ++t) acc2[t] /= ldiv;
  } else {
    float m[4] = {NEG_BIG, NEG_BIG, NEG_BIG, NEG_BIG};
    for (int i0 = 0; i0 < nn; i0 += 64) {
      float s[4] = {NEG_BIG, NEG_BIG, NEG_BIG, NEG_BIG};
      if (i0 + lane < nn) score4(nbr[wv][i0 + lane], s);
#pragma unroll
      for (int h = 0; h < 4; ++h) m[h] = fmaxf(m[h], s[h]);
    }
#pragma unroll
    for (int h = 0; h < 4; ++h) {
      for (int off = 32; off; off >>= 1) m[h] = fmaxf(m[h], __shfl_down(m[h], off));
      m[h] = __shfl(m[h], 0);
    }
    float l[4] = {0.f, 0.f, 0.f, 0.f};
    for (int i0 = 0; i0 < nn; i0 += 64) {
      float s[4] = {NEG_BIG, NEG_BIG, NEG_BIG, NEG_BIG};
      if (i0 + lane < nn) score4(nbr[wv][i0 + lane], s);
      float e[4];
#pragma unroll
      for (int h = 0; h < 4; ++h) {
        e[h] = (i0 + lane < nn) ? __expf(s[h] - m[h]) : 0.f;
        float ls = e[h];
        for (int off = 32; off; off >>= 1) ls += __shfl_down(ls, off);
        l[h] += __shfl(ls, 0);
      }
      auto picke = [&](int ii) {
        float a0 = __shfl(e[0], ii), a1 = __shfl(e[1], ii);
        float a2 = __shfl(e[2], ii), a3 = __shfl(e[3], ii);
        return hl == 0 ? a0 : (hl == 1 ? a1 : (hl == 2 ? a2 : a3));
      };
      int lim = min(64, nn - i0);
      for (int ii = 0; ii < lim; ++ii) {
        bf16x4 v0 = *(const bf16x4*)(base + (size_t)nbr[wv][i0 + ii] * 768 + 512 + lane * 4);
        float w0 = picke(ii);
#pragma unroll
        for (int t = 0; t < 4; ++t) acc2[t] += w0 * (float)v0[t];
      }
    }
    float ldiv = hl == 0 ? l[0] : (hl == 1 ? l[1] : (hl == 2 ? l[2] : l[3]));
#pragma unroll
    for (int t = 0; t < 4; ++t) acc2[t] /= ldiv;
  }
  // output: lane*4+t == hl*64 + d — same (h,d) mapping as the old scalar path
  bf16x4 hi4, lo4;
#pragma unroll
  for (int t = 0; t < 4; ++t) {
    float a = acc2[t];
    bf16 h8 = (bf16)a;
    hi4[t] = h8;
    lo4[t] = (bf16)(a - (float)h8);
  }
  *(bf16x4*)(aos + (size_t)bn * 512 + lane * 4) = hi4;
  *(bf16x4*)(aos + (size_t)bn * 512 + 256 + lane * 4) = lo4;
}

// ---------------------------------------------------------------------------
// fused out-projection + bias + residual + LayerNorm -> out.
// 32 rows x 256 cols per block (grid 256), BK=32, LDS dbuf, swizzle
// (r>>1)&3.  Per-row LN: 16-lane shuffle + 4-wave LDS combine.
// ---------------------------------------------------------------------------
__global__ __launch_bounds__(256) void projln_kernel(const bf16* __restrict__ A,
                                                     const bf16* __restrict__ Bw,
                                                     const float* __restrict__ x,
                                                     const float* __restrict__ bo,
                                                     const float* __restrict__ gamma,
                                                     const float* __restrict__ beta,
                                                     float* __restrict__ out) {
  __shared__ bf16 As[2 * 32 * 32];     // 4 KB
  __shared__ bf16 Bs[2 * 256 * 32];    // 32 KB
  __shared__ float rsum[32][4];
  __shared__ float rsq[32][4];
  int tid = threadIdx.x;
  int lane = tid & 63;
  int wv = tid >> 6;
  int wn = wv * 64;                    // each wave: all 32 rows x 64 cols
  int row0 = blockIdx.x * 32;

  int rt = tid >> 2;                   // B row helper 0..63
  int ra = tid >> 2;                   // A row 0..31 (tid<128)
  int gpa = (tid & 3) ^ ((ra >> 1) & 3);
  const bf16* ga0 = A + (size_t)(row0 + ra) * 512 + gpa * 8;

  int fr = lane & 15;
  int G = lane >> 4;

  f32x4 acc[2][4] = {};

  auto issue = [&](int st, int buf) {
    int aoff = ((st >> 3) << 8) | ((st & 7) << 5);  // A: ch0 h, ch1 m
    int boff = (st & 7) << 5;                       // B: h only
    if (tid < 128)
      async_cp16(ga0 + aoff, &As[buf * 1024 + tid * 8]);
#pragma unroll
    for (int q = 0; q < 4; ++q) {
      int rb = q * 64 + rt;
      int gpb = (tid & 3) ^ ((rb >> 1) & 3);
      async_cp16(Bw + (size_t)rb * 512 + gpb * 8 + boff,
                 &Bs[buf * 8192 + (q * 256 + tid) * 8]);
    }
  };

  issue(0, 0);
  for (int st = 0; st < 16; ++st) {
    int buf = st & 1;
    if (st + 1 < 16) {
      issue(st + 1, buf ^ 1);
      WAITVM(4);  // waves 2-3: exactly st retired; waves 0-1: slightly stricter
    } else {
      WAITVM(0);
    }
    __builtin_amdgcn_s_barrier();
    bf16x8 af[2], bfr[4];
#pragma unroll
    for (int mi = 0; mi < 2; ++mi) {
      int r = mi * 16 + fr;
      af[mi] = *(const bf16x8*)&As[buf * 1024 + r * 32 + ((G ^ ((r >> 1) & 3)) << 3)];
    }
#pragma unroll
    for (int nj = 0; nj < 4; ++nj) {
      int r = wn + nj * 16 + fr;
      bfr[nj] = *(const bf16x8*)&Bs[buf * 8192 + r * 32 + ((G ^ ((r >> 1) & 3)) << 3)];
    }
#pragma unroll
    for (int mi = 0; mi < 2; ++mi)
#pragma unroll
      for (int nj = 0; nj < 4; ++nj)
        acc[mi][nj] = __builtin_amdgcn_mfma_f32_16x16x32_bf16(af[mi], bfr[nj], acc[mi][nj], 0, 0, 0);
    __builtin_amdgcn_s_barrier();
  }

  int er = (lane >> 4) * 4;
  int ec = lane & 15;
  float bo_c[4], ga_c[4], be_c[4];
#pragma unroll
  for (int nj = 0; nj < 4; ++nj) {
    int c = wn + nj * 16 + ec;
    bo_c[nj] = bo[c]; ga_c[nj] = gamma[c]; be_c[nj] = beta[c];
  }
#pragma unroll
  for (int mi = 0; mi < 2; ++mi)
#pragma unroll
    for (int reg = 0; reg < 4; ++reg) {
      int rloc = mi * 16 + er + reg;
      const float* xr = x + (size_t)(row0 + rloc) * D;
      float su = 0.f, s2 = 0.f;
#pragma unroll
      for (int nj = 0; nj < 4; ++nj) {
        float u = acc[mi][nj][reg] + bo_c[nj] + xr[wn + nj * 16 + ec];
        su += u; s2 += u * u;
      }
#pragma unroll
      for (int m = 1; m <= 8; m <<= 1) {
        su += __shfl_xor(su, m);
        s2 += __shfl_xor(s2, m);
      }
      if (ec == 0) { rsum[rloc][wv] = su; rsq[rloc][wv] = s2; }
    }
  __syncthreads();
#pragma unroll
  for (int mi = 0; mi < 2; ++mi)
#pragma unroll
    for (int reg = 0; reg < 4; ++reg) {
      int rloc = mi * 16 + er + reg;
      float s = rsum[rloc][0] + rsum[rloc][1] + rsum[rloc][2] + rsum[rloc][3];
      float q2 = rsq[rloc][0] + rsq[rloc][1] + rsq[rloc][2] + rsq[rloc][3];
      float mean = s * (1.0f / D);
      float var = q2 * (1.0f / D) - mean * mean;
      float rstd = rsqrtf(var + 1e-5f);
      const float* xr = x + (size_t)(row0 + rloc) * D;
      float* orow = out + (size_t)(row0 + rloc) * D;
#pragma unroll
      for (int nj = 0; nj < 4; ++nj) {
        float u = acc[mi][nj][reg] + bo_c[nj] + xr[wn + nj * 16 + ec];
        orow[wn + nj * 16 + ec] = (u - mean) * rstd * ga_c[nj] + be_c[nj];
      }
    }
}

// ---------------------------------------------------------------------------
// Workspace.  Common: XsN [0,8.39M) | sim [12.58M,79.69M) | norms@79.69M
//                     mask@79.99M | Wt@82.08M (ends 83,132,416)
// BIG (ws >= 125 MB): qkv(bf16)@83.13M | aos@95.72M
// SMALL: qkv@12.58M, aos@37.75M (dead-sim region, written after topk)
// ---------------------------------------------------------------------------
extern "C" void kernel_launch(void* const* d_in, const int* in_sizes, int n_in,
                              void* d_out, int out_size, void* d_ws, size_t ws_size,
                              hipStream_t stream) {
  const float* x     = (const float*)d_in[0];
  const float* Wq    = (const float*)d_in[1];
  const float* Wk    = (const float*)d_in[2];
  const float* Wv    = (const float*)d_in[3];
  const float* Wo    = (const float*)d_in[4];
  const float* bo    = (const float*)d_in[5];
  const float* gamma = (const float*)d_in[6];
  const float* beta  = (const float*)d_in[7];
  float* out = (float*)d_out;

  char* ws = (char*)d_ws;
  bf16* XsN      = (bf16*)(ws);
  float* sim     = (float*)(ws + 12582912);
  float* norms   = (float*)(ws + 79691776);
  unsigned* mask = (unsigned*)(ws + 79986688);
  bf16* Wt       = (bf16*)(ws + 82083840);

  bool big = ws_size >= (size_t)125000000;
  bf16* qkv = (bf16*)(ws + (big ? 83132416 : 12582912));
  bf16* aos = (bf16*)(ws + (big ? 95715328 : 37748736));

  const int AMAP_SIM = PK6(0, 0, 1, 0, 0, 0);  // hh + hm + mh
  const int BMAP_SIM = PK6(0, 1, 0, 0, 0, 0);
  const int AMAP_2T  = PK3(0, 1, 0);           // (h+m)_A · h_B
  const int BMAP_2T  = PK3(0, 0, 1);

  prep_kernel<<<8384, 64, 0, stream>>>(x, Wq, Wk, Wv, Wo, XsN, Wt, norms,
                                       (uint4*)mask);

  if (big) {
    gemm_fused128x256_kernel<<<480, 256, 0, stream>>>(
        XsN, sim, AMAP_SIM, BMAP_SIM, Wt, qkv, AMAP_2T, BMAP_2T, norms);
    topk_adj_kernel<<<2048, 256, 0, stream>>>(sim, mask);
  } else {
    gemm_sim_kernel<<<544, 256, 0, stream>>>(XsN, sim, AMAP_SIM, BMAP_SIM);
    topk_adj_kernel<<<2048, 256, 0, stream>>>(sim, mask);
    gemm_qkv_kernel<<<dim3(6, 64), 256, 0, stream>>>(XsN, Wt, qkv,
                                                     AMAP_2T, BMAP_2T, norms);
  }

  attn_kernel<<<(BATCH * N) / 4, 256, 0, stream>>>(qkv, mask, aos);

  projln_kernel<<<256, 256, 0, stream>>>(aos, Wt + (size_t)768 * 512,
                                         x, bo, gamma, beta, out);
}

// Round 10
// 187.638 us; speedup vs baseline: 1.2366x; 1.2366x over previous
//
#include <hip/hip_runtime.h>
#include <hip/hip_bf16.h>
#include <math.h>

#define BATCH 4
#define N 2048
#define D 256
#define NH 4
#define DH 64
#define TOPK 9
#define NEG_BIG -1e30f

typedef __bf16 bf16;
typedef __bf16 bf16x4 __attribute__((ext_vector_type(4)));
typedef __bf16 bf16x8 __attribute__((ext_vector_type(8)));
typedef float f32x4 __attribute__((ext_vector_type(4)));

#define PK3(a,b,c) ((a) | ((b) << 2) | ((c) << 4))
#define PK6(a,b,c,d,e,f) ((a) | ((b) << 2) | ((c) << 4) | ((d) << 6) | ((e) << 8) | ((f) << 10))

// s_waitcnt with ONLY vmcnt=N. gfx9 encoding: vmcnt[3:0]@0, expcnt@4,
// lgkmcnt@8, vmcnt[5:4]@14.
#define WAITVM(Nc) __builtin_amdgcn_s_waitcnt((((Nc) & 0xf)) | (7u << 4) | (0xfu << 8) | ((((unsigned)(Nc)) >> 4) << 14))

__device__ __forceinline__ void async_cp16(const bf16* g, const bf16* l) {
  __builtin_amdgcn_global_load_lds(
      (const __attribute__((address_space(1))) void*)(uintptr_t)g,
      (__attribute__((address_space(3))) void*)(uintptr_t)l, 16, 0, 0);
}

// ---------------------------------------------------------------------------
// prep: blk<8192: x -> XsN (L2-norm, 2-way split h/m, stride 512) + norms
//       blk<8256: W{q,k,v,o} -> Wt via coalesced 64x64 LDS transpose
//       else (128 blks): zero the 2 MB adjacency mask
// ---------------------------------------------------------------------------
__global__ __launch_bounds__(64) void prep_kernel(const float* __restrict__ x,
                                                  const float* __restrict__ Wq,
                                                  const float* __restrict__ Wk,
                                                  const float* __restrict__ Wv,
                                                  const float* __restrict__ Wo,
                                                  bf16* __restrict__ XsN,
                                                  bf16* __restrict__ Wt,
                                                  float* __restrict__ norms,
                                                  uint4* __restrict__ mask4) {
  __shared__ float T[64][65];
  int blk = blockIdx.x;
  int lane = threadIdx.x;
  if (blk < 8192) {
    float4 v = *(const float4*)(x + (size_t)blk * D + lane * 4);
    float ss = v.x * v.x + v.y * v.y + v.z * v.z + v.w * v.w;
    for (int off = 32; off; off >>= 1) ss += __shfl_down(ss, off);
    ss = __shfl(ss, 0);
    float nrm = fmaxf(sqrtf(ss), 1e-12f);
    if (lane == 0) norms[blk] = nrm;
    float sc = 1.0f / nrm;
    float xs[4] = {v.x * sc, v.y * sc, v.z * sc, v.w * sc};
    bf16* o = XsN + (size_t)blk * 512 + lane * 4;
#pragma unroll
    for (int j = 0; j < 4; ++j) {
      float xv = xs[j];
      bf16 h = (bf16)xv;
      o[j] = h;
      o[256 + j] = (bf16)(xv - (float)h);
    }
  } else if (blk < 8256) {
    int tj = blk - 8192;            // 0..63: 4 W x 16 (64x64) tiles
    int wsel = tj >> 4;
    int tile = tj & 15;
    int tr = (tile >> 2) * 64;      // k range
    int tc = (tile & 3) * 64;       // j range
    const float* W = (wsel == 0) ? Wq : (wsel == 1) ? Wk : (wsel == 2) ? Wv : Wo;
    int l4 = lane & 15, lr = lane >> 4;
#pragma unroll
    for (int it = 0; it < 16; ++it) {
      int k = tr + it * 4 + lr;
      float4 w4 = *(const float4*)(W + (size_t)k * D + tc + l4 * 4);
      T[l4 * 4 + 0][it * 4 + lr] = w4.x;   // T[j'][k'] = W[tr+k'][tc+j']
      T[l4 * 4 + 1][it * 4 + lr] = w4.y;
      T[l4 * 4 + 2][it * 4 + lr] = w4.z;
      T[l4 * 4 + 3][it * 4 + lr] = w4.w;
    }
    __syncthreads();
    int jj = wsel * 256 + tc + lane;
    bf16* dst = Wt + (size_t)jj * 512 + tr;
#pragma unroll
    for (int c = 0; c < 8; ++c) {
      bf16x8 hv, mv;
#pragma unroll
      for (int t = 0; t < 8; ++t) {
        float w = T[lane][c * 8 + t];
        bf16 h = (bf16)w;
        hv[t] = h;
        mv[t] = (bf16)(w - (float)h);
      }
      *(bf16x8*)(dst + c * 8) = hv;
      *(bf16x8*)(dst + 256 + c * 8) = mv;
    }
  } else {
    int base = (blk - 8256) * 1024 + lane;
#pragma unroll
    for (int t = 0; t < 16; ++t)
      mask4[base + t * 64] = make_uint4(0, 0, 0, 0);
  }
}

// ---------------------------------------------------------------------------
// 128x256 4-wave GEMM core (round 5 PROVEN: 43us).  BK=32, counted WAITVM(6),
// swizzle (r>>1)&3, 2 blk/CU.
// outmode 1: fp32 nontemporal + optional mirror (f32x4 vector store).
// outmode 2: bf16 with per-row norm rescale (qkv).
// ---------------------------------------------------------------------------
__device__ __forceinline__ void gemm_core128x256(bf16* As, bf16* Bs,
                                                 const bf16* __restrict__ Ab,
                                                 const bf16* __restrict__ Bb,
                                                 void* __restrict__ Cvoid,
                                                 int ldc, int nsteps,
                                                 int amap, int bmap,
                                                 int row0, int col0,
                                                 int outmode, bool mirror,
                                                 const float* __restrict__ rowscale) {
  int tid = threadIdx.x;
  int lane = tid & 63;
  int wv = tid >> 6;            // 4 waves: 2M x 2N
  int wm = (wv >> 1) * 64;      // wave rows: 64 of 128
  int wn = (wv & 1) * 128;      // wave cols: 128 of 256
  int fr = lane & 15;
  int G = lane >> 4;            // k-slot 0..3 (8 bf16 each)

  f32x4 acc[4][8] = {};

  auto issue = [&](int st, int buf) {
    int ch = st >> 3;                                        // 256-K chunk
    int aoff = (((amap >> (ch * 2)) & 3) << 8) | ((st & 7) << 5);
    int boff = (((bmap >> (ch * 2)) & 3) << 8) | ((st & 7) << 5);
    // A: 128x32 = 512 16B-slots, 2/thread
#pragma unroll
    for (int q = 0; q < 2; ++q) {
      int s = q * 256 + tid;
      int r = s >> 2, sl = s & 3;
      async_cp16(Ab + (size_t)r * 512 + ((sl ^ ((r >> 1) & 3)) << 3) + aoff,
                 &As[buf * 4096 + s * 8]);
    }
    // B: 256x32 = 1024 16B-slots, 4/thread
#pragma unroll
    for (int q = 0; q < 4; ++q) {
      int s = q * 256 + tid;
      int r = s >> 2, sl = s & 3;
      async_cp16(Bb + (size_t)r * 512 + ((sl ^ ((r >> 1) & 3)) << 3) + boff,
                 &Bs[buf * 8192 + s * 8]);
    }
  };

  issue(0, 0);
  for (int st = 0; st < nsteps; ++st) {
    int buf = st & 1;
    if (st + 1 < nsteps) {
      issue(st + 1, buf ^ 1);
      WAITVM(6);        // exactly the 6 just-issued outstanding; tile st landed
    } else {
      WAITVM(0);
    }
    __builtin_amdgcn_s_barrier();
    bf16x8 af[4], bfr[8];
#pragma unroll
    for (int mi = 0; mi < 4; ++mi) {
      int r = wm + mi * 16 + fr;
      af[mi] = *(const bf16x8*)&As[buf * 4096 + r * 32 + ((G ^ ((r >> 1) & 3)) << 3)];
    }
#pragma unroll
    for (int nj = 0; nj < 8; ++nj) {
      int r = wn + nj * 16 + fr;
      bfr[nj] = *(const bf16x8*)&Bs[buf * 8192 + r * 32 + ((G ^ ((r >> 1) & 3)) << 3)];
    }
    __builtin_amdgcn_s_setprio(1);
#pragma unroll
    for (int mi = 0; mi < 4; ++mi)
#pragma unroll
      for (int nj = 0; nj < 8; ++nj)
        acc[mi][nj] = __builtin_amdgcn_mfma_f32_16x16x32_bf16(af[mi], bfr[nj], acc[mi][nj], 0, 0, 0);
    __builtin_amdgcn_s_setprio(0);
    __builtin_amdgcn_s_barrier();
  }

  int er = (lane >> 4) * 4;
  int ec = lane & 15;
#pragma unroll
  for (int mi = 0; mi < 4; ++mi) {
    int rb = row0 + wm + mi * 16 + er;
    float scl[4] = {1.f, 1.f, 1.f, 1.f};
    if (rowscale) {
      float4 s4 = *(const float4*)(rowscale + rb);
      scl[0] = s4.x; scl[1] = s4.y; scl[2] = s4.z; scl[3] = s4.w;
    }
#pragma unroll
    for (int nj = 0; nj < 8; ++nj) {
      int cb = col0 + wn + nj * 16 + ec;
      if (outmode == 1) {
        float* Cb = (float*)Cvoid;
#pragma unroll
        for (int reg = 0; reg < 4; ++reg)
          __builtin_nontemporal_store(acc[mi][nj][reg],
                                      &Cb[(size_t)(rb + reg) * ldc + cb]);
        if (mirror) {
          // mirrored: 4 consecutive rows -> contiguous col-major addresses
          __builtin_nontemporal_store(acc[mi][nj],
                                      (f32x4*)&Cb[(size_t)cb * ldc + rb]);
        }
      } else {
        bf16* Cb = (bf16*)Cvoid;
#pragma unroll
        for (int reg = 0; reg < 4; ++reg)
          Cb[(size_t)(rb + reg) * ldc + cb] = (bf16)(acc[mi][nj][reg] * scl[reg]);
      }
    }
  }
}

// fused sim + qkv, 128x256 tiles: 288 sim (24-step) + 192 qkv (16-step).
// SSQSQ dispatch interleave (round 8) — each CU's 2 resident blocks average
// ~40 steps.  Decode unchanged.
__global__ __launch_bounds__(256, 2) void gemm_fused128x256_kernel(
    const bf16* __restrict__ XsN, float* __restrict__ sim,
    int amap_s, int bmap_s,
    const bf16* __restrict__ Wt, bf16* __restrict__ qkv,
    int amap_q, int bmap_q, const float* __restrict__ norms) {
  __shared__ bf16 As[2 * 128 * 32];   // 16 KB
  __shared__ bf16 Bs[2 * 256 * 32];   // 32 KB
  int g = blockIdx.x;                 // 0..479 = 5 * 96
  int rr = g % 5, u = g / 5;
  if (rr == 0 || rr == 1 || rr == 3) {
    int s = u * 3 + (rr == 3 ? 2 : rr);  // 0..287
    int xcd = s & 7;
    int z = xcd >> 1;
    int t = (xcd & 1) * 36 + (s >> 3);   // 0..71 within batch
    int half = t & 1;
    int uu = t >> 1;                     // supertile 0..35
    int by = 0;
    while (uu >= 8 - by) { uu -= 8 - by; ++by; }
    int bx = by + uu;
    int row0 = by * 256 + half * 128;
    int col0 = bx * 256;
    gemm_core128x256(As, Bs,
                     XsN + (size_t)z * N * 512 + (size_t)row0 * 512,
                     XsN + (size_t)z * N * 512 + (size_t)col0 * 512,
                     sim + (size_t)z * N * N,
                     N, 24, amap_s, bmap_s, row0, col0,
                     1, bx != by, nullptr);
  } else {
    int q = u * 2 + (rr == 4 ? 1 : 0);   // 0..191
    int xcd = q & 7;
    int slot = q >> 3;                   // 0..23
    int z = xcd >> 1;
    int by = z * 16 + (xcd & 1) * 8 + slot / 3;  // 0..63 global 128-row tiles
    int bx = slot % 3;
    gemm_core128x256(As, Bs,
                     XsN + (size_t)by * 128 * 512,
                     Wt + (size_t)bx * 256 * 512,
                     qkv, 768, 16, amap_q, bmap_q,
                     by * 128, bx * 256, 2, false, norms);
  }
}

// ---------------------------------------------------------------------------
// 128^2 GEMM core — small-ws fallback.
// ---------------------------------------------------------------------------
__device__ __forceinline__ void gemm_core(bf16* As, bf16* Bs,
                                          const bf16* __restrict__ Ab,
                                          const bf16* __restrict__ Bb,
                                          void* __restrict__ Cvoid,
                                          int lda, int ldb, int ldc,
                                          int nsteps, int amap, int bmap,
                                          int row0, int col0,
                                          int outmode, bool mirror,
                                          const float* __restrict__ rowscale) {
  int tid = threadIdx.x;
  int lane = tid & 63;
  int wv = tid >> 6;
  int wm = (wv >> 1) * 64;
  int wn = (wv & 1) * 64;

  int rbase = tid >> 2;
  int gperm = (tid & 3) ^ ((rbase >> 1) & 3);
  const bf16* ga0 = Ab + (size_t)rbase * lda + gperm * 8;
  const bf16* gb0 = Bb + (size_t)rbase * ldb + gperm * 8;
  int ldsoff = tid * 8;

  int fr = lane & 15;
  int G = lane >> 4;

  f32x4 acc[4][4] = {};

  auto issue = [&](int st, int buf) {
    int ch = st >> 3;
    int aoff = (((amap >> (ch * 2)) & 3) << 8) | ((st & 7) << 5);
    int boff = (((bmap >> (ch * 2)) & 3) << 8) | ((st & 7) << 5);
#pragma unroll
    for (int q = 0; q < 2; ++q)
      async_cp16(ga0 + (size_t)q * 64 * lda + aoff, &As[buf * 4096 + ldsoff + q * 2048]);
#pragma unroll
    for (int q = 0; q < 2; ++q)
      async_cp16(gb0 + (size_t)q * 64 * ldb + boff, &Bs[buf * 4096 + ldsoff + q * 2048]);
  };

  issue(0, 0);
  for (int st = 0; st < nsteps; ++st) {
    int buf = st & 1;
    if (st + 1 < nsteps) {
      issue(st + 1, buf ^ 1);
      WAITVM(4);
    } else {
      WAITVM(0);
    }
    __builtin_amdgcn_s_barrier();
    bf16x8 af[4], bfr[4];
#pragma unroll
    for (int mi = 0; mi < 4; ++mi) {
      int r = wm + mi * 16 + fr;
      af[mi] = *(const bf16x8*)&As[buf * 4096 + r * 32 + ((G ^ ((r >> 1) & 3)) << 3)];
    }
#pragma unroll
    for (int nj = 0; nj < 4; ++nj) {
      int r = wn + nj * 16 + fr;
      bfr[nj] = *(const bf16x8*)&Bs[buf * 4096 + r * 32 + ((G ^ ((r >> 1) & 3)) << 3)];
    }
#pragma unroll
    for (int mi = 0; mi < 4; ++mi)
#pragma unroll
      for (int nj = 0; nj < 4; ++nj)
        acc[mi][nj] = __builtin_amdgcn_mfma_f32_16x16x32_bf16(af[mi], bfr[nj], acc[mi][nj], 0, 0, 0);
    __builtin_amdgcn_s_barrier();
  }

  int er = (lane >> 4) * 4;
  int ec = lane & 15;
#pragma unroll
  for (int mi = 0; mi < 4; ++mi) {
    int rb = row0 + wm + mi * 16 + er;
    float scl[4] = {1.f, 1.f, 1.f, 1.f};
    if (rowscale) {
      float4 s4 = *(const float4*)(rowscale + rb);
      scl[0] = s4.x; scl[1] = s4.y; scl[2] = s4.z; scl[3] = s4.w;
    }
#pragma unroll
    for (int nj = 0; nj < 4; ++nj) {
      int cb = col0 + wn + nj * 16 + ec;
      if (outmode == 1) {
        float* Cb = (float*)Cvoid;
#pragma unroll
        for (int reg = 0; reg < 4; ++reg)
          __builtin_nontemporal_store(acc[mi][nj][reg],
                                      &Cb[(size_t)(rb + reg) * ldc + cb]);
        if (mirror) {
#pragma unroll
          for (int reg = 0; reg < 4; ++reg)
            __builtin_nontemporal_store(acc[mi][nj][reg],
                                        &Cb[(size_t)cb * ldc + rb + reg]);
        }
      } else {
        bf16* Cb = (bf16*)Cvoid;
#pragma unroll
        for (int reg = 0; reg < 4; ++reg)
          Cb[(size_t)(rb + reg) * ldc + cb] = (bf16)(acc[mi][nj][reg] * scl[reg]);
      }
    }
  }
}

// sim-only dispatch (small-ws fallback): grid (544)
__global__ __launch_bounds__(256, 4) void gemm_sim_kernel(const bf16* __restrict__ XsN,
                                                          float* __restrict__ sim,
                                                          int amap, int bmap) {
  __shared__ bf16 As[2 * 128 * 32];
  __shared__ bf16 Bs[2 * 128 * 32];
  int g = blockIdx.x;
  int xcd = g & 7;
  int slot = g >> 3;
  int z = xcd >> 1;
  int t = (xcd & 1) * 68 + slot;
  int by = 0;
  while (t >= 16 - by) { t -= 16 - by; ++by; }
  int bx = by + t;
  gemm_core(As, Bs,
            XsN + (size_t)z * N * 512 + (size_t)by * 128 * 512,
            XsN + (size_t)z * N * 512 + (size_t)bx * 128 * 512,
            sim + (size_t)z * N * N,
            512, 512, N, 24, amap, bmap, by * 128, bx * 128,
            1, bx != by, nullptr);
}

// generic qkv dispatch (small-ws fallback): grid (6, 64), bf16 out
__global__ __launch_bounds__(256, 4) void gemm_qkv_kernel(const bf16* __restrict__ XsN,
                                                          const bf16* __restrict__ Wt,
                                                          bf16* __restrict__ qkv,
                                                          int amap, int bmap,
                                                          const float* __restrict__ norms) {
  __shared__ bf16 As[2 * 128 * 32];
  __shared__ bf16 Bs[2 * 128 * 32];
  gemm_core(As, Bs,
            XsN + (size_t)blockIdx.y * 128 * 512,
            Wt + (size_t)blockIdx.x * 128 * 512,
            qkv, 512, 512, 768, 16, amap, bmap,
            blockIdx.y * 128, blockIdx.x * 128, 2, false, norms);
}

// ---------------------------------------------------------------------------
// top-9 per row by 9x extract-max, fused adjacency write.  One wave per
// 64-thread block (round-7 PROVEN ~25us variant).  Rounds 8/9 lesson: with
// 256-thread blocks the compiler caps this kernel at 48 VGPR and spills
// v[32] (44us and 84us).  Keep 64-thread blocks; no register-sensitive
// cleverness without compile-time VGPR verification.
// ---------------------------------------------------------------------------
__global__ __launch_bounds__(64) void topk_adj_kernel(const float* __restrict__ sim,
                                                      unsigned* __restrict__ mask) {
  int row = blockIdx.x;
  int lane = threadIdx.x;
  int b = row >> 11, r = row & 2047;
  const float* srow = sim + (size_t)row * N;
  float v[32];
#pragma unroll
  for (int it = 0; it < 8; ++it) {
    float4 q = *(const float4*)(srow + it * 256 + lane * 4);
    v[it * 4 + 0] = q.x; v[it * 4 + 1] = q.y;
    v[it * 4 + 2] = q.z; v[it * 4 + 3] = q.w;
  }
  unsigned removed = 0;
  for (int rs = 0; rs < TOPK; ++rs) {
    float m = -3e38f;
    int mi = 0;
#pragma unroll
    for (int i = 0; i < 32; ++i) {
      float vv = ((removed >> i) & 1u) ? -3e38f : v[i];
      if (vv > m) { m = vv; mi = i; }
    }
    int gidx = ((mi >> 2) << 8) + lane * 4 + (mi & 3);
    for (int off = 32; off; off >>= 1) {
      float om = __shfl_down(m, off);
      int og = __shfl_down(gidx, off);
      if (om > m || (om == m && og < gidx)) { m = om; gidx = og; }
    }
    gidx = __shfl(gidx, 0);
    if (((gidx >> 2) & 63) == lane)
      removed |= 1u << (((gidx >> 8) << 2) | (gidx & 3));
    if (lane == 0) {
      atomicOr(&mask[(size_t)row * 64 + (gidx >> 5)], 1u << (gidx & 31));
      atomicOr(&mask[(((size_t)b << 11) + gidx) * 64 + (r >> 5)], 1u << (r & 31));
    }
  }
}

// ---------------------------------------------------------------------------
// sparse attention: 4 waves/block, one (b,n) row per wave; XCD-aware decode.
// PV relayout (round 7): lane l owns dims (l&15)*4..+3 of head l>>4; one
// bf16x4 V load per neighbor.  Accumulation order per (h,d) unchanged.
// ---------------------------------------------------------------------------
__global__ __launch_bounds__(256) void attn_kernel(const bf16* __restrict__ qkv,
                                                   const unsigned* __restrict__ mask,
                                                   bf16* __restrict__ aos) {
  __shared__ float sq[4][256];
  __shared__ unsigned short nbr[4][2048];
  __shared__ int s_nn[4];
  int wv = threadIdx.x >> 6;
  int lane = threadIdx.x & 63;
  int hl = lane >> 4;                 // my head for PV/output
  int g = blockIdx.x;
  int xcd = g & 7;
  int b = xcd >> 1;
  int tile = (xcd & 1) * 256 + (g >> 3);
  int bn = b * N + tile * 4 + wv;
  if (lane == 0) s_nn[wv] = 0;
  {
    bf16x4 qv = *(const bf16x4*)(qkv + (size_t)bn * 768 + lane * 4);
#pragma unroll
    for (int j = 0; j < 4; ++j) sq[wv][lane * 4 + j] = (float)qv[j];
  }
  __syncthreads();
  unsigned bits = mask[(size_t)bn * (N / 32) + lane];
  while (bits) {
    int bit = __ffs(bits) - 1;
    bits &= bits - 1;
    int p = atomicAdd(&s_nn[wv], 1);
    nbr[wv][p] = (unsigned short)(lane * 32 + bit);
  }
  __syncthreads();
  int nn = s_nn[wv];
  const bf16* base = qkv + (size_t)b * N * 768;
  float acc2[4] = {0.f, 0.f, 0.f, 0.f};   // dims (lane&15)*4+{0..3} of head hl

  auto score4 = [&](int j, float* s) {
    const bf16* kr = base + (size_t)j * 768 + 256;
#pragma unroll
    for (int h = 0; h < 4; ++h) {
      float a = 0.f;
#pragma unroll
      for (int c = 0; c < DH; c += 8) {
        bf16x8 kk = *(const bf16x8*)(kr + h * DH + c);
#pragma unroll
        for (int t = 0; t < 8; ++t) a += sq[wv][h * DH + c + t] * (float)kk[t];
      }
      s[h] = a * 0.125f;
    }
  };

  if (nn <= 64) {
    float s[4] = {NEG_BIG, NEG_BIG, NEG_BIG, NEG_BIG};
    if (lane < nn) score4(nbr[wv][lane], s);
    float w[4], l[4];
#pragma unroll
    for (int h = 0; h < 4; ++h) {
      float m = s[h];
      for (int off = 32; off; off >>= 1) m = fmaxf(m, __shfl_down(m, off));
      m = __shfl(m, 0);
      float e = (lane < nn) ? __expf(s[h] - m) : 0.f;
      float ls = e;
      for (int off = 32; off; off >>= 1) ls += __shfl_down(ls, off);
      l[h] = __shfl(ls, 0);
      w[h] = e;
    }
    auto pickw = [&](int ii) {
      float a0 = __shfl(w[0], ii), a1 = __shfl(w[1], ii);
      float a2 = __shfl(w[2], ii), a3 = __shfl(w[3], ii);
      return hl == 0 ? a0 : (hl == 1 ? a1 : (hl == 2 ? a2 : a3));
    };
    int i = 0;
    for (; i + 4 <= nn; i += 4) {
      int j0 = nbr[wv][i + 0], j1 = nbr[wv][i + 1];
      int j2 = nbr[wv][i + 2], j3 = nbr[wv][i + 3];
      bf16x4 v0 = *(const bf16x4*)(base + (size_t)j0 * 768 + 512 + lane * 4);
      bf16x4 v1 = *(const bf16x4*)(base + (size_t)j1 * 768 + 512 + lane * 4);
      bf16x4 v2 = *(const bf16x4*)(base + (size_t)j2 * 768 + 512 + lane * 4);
      bf16x4 v3 = *(const bf16x4*)(base + (size_t)j3 * 768 + 512 + lane * 4);
      float w0 = pickw(i + 0), w1 = pickw(i + 1);
      float w2 = pickw(i + 2), w3 = pickw(i + 3);
#pragma unroll
      for (int t = 0; t < 4; ++t)
        acc2[t] += w0 * (float)v0[t] + w1 * (float)v1[t] +
                   w2 * (float)v2[t] + w3 * (float)v3[t];
    }
    for (; i < nn; ++i) {
      bf16x4 v0 = *(const bf16x4*)(base + (size_t)nbr[wv][i] * 768 + 512 + lane * 4);
      float w0 = pickw(i);
#pragma unroll
      for (int t = 0; t < 4; ++t) acc2[t] += w0 * (float)v0[t];
    }
    float ldiv = hl == 0 ? l[0] : (hl == 1 ? l[1] : (hl == 2 ? l[2] : l[3]));
#pragma unroll
    for (int t = 0; t < 4; ++t) acc2[t] /= ldiv;
  } else {
    float m[4] = {NEG_BIG, NEG_BIG, NEG_BIG, NEG_BIG};
    for (int i0 = 0; i0 < nn; i0 += 64) {
      float s[4] = {NEG_BIG, NEG_BIG, NEG_BIG, NEG_BIG};
      if (i0 + lane < nn) score4(nbr[wv][i0 + lane], s);
#pragma unroll
      for (int h = 0; h < 4; ++h) m[h] = fmaxf(m[h], s[h]);
    }
#pragma unroll
    for (int h = 0; h < 4; ++h) {
      for (int off = 32; off; off >>= 1) m[h] = fmaxf(m[h], __shfl_down(m[h], off));
      m[h] = __shfl(m[h], 0);
    }
    float l[4] = {0.f, 0.f, 0.f, 0.f};
    for (int i0 = 0; i0 < nn; i0 += 64) {
      float s[4] = {NEG_BIG, NEG_BIG, NEG_BIG, NEG_BIG};
      if (i0 + lane < nn) score4(nbr[wv][i0 + lane], s);
      float e[4];
#pragma unroll
      for (int h = 0; h < 4; ++h) {
        e[h] = (i0 + lane < nn) ? __expf(s[h] - m[h]) : 0.f;
        float ls = e[h];
        for (int off = 32; off; off >>= 1) ls += __shfl_down(ls, off);
        l[h] += __shfl(ls, 0);
      }
      auto picke = [&](int ii) {
        float a0 = __shfl(e[0], ii), a1 = __shfl(e[1], ii);
        float a2 = __shfl(e[2], ii), a3 = __shfl(e[3], ii);
        return hl == 0 ? a0 : (hl == 1 ? a1 : (hl == 2 ? a2 : a3));
      };
      int lim = min(64, nn - i0);
      for (int ii = 0; ii < lim; ++ii) {
        bf16x4 v0 = *(const bf16x4*)(base + (size_t)nbr[wv][i0 + ii] * 768 + 512 + lane * 4);
        float w0 = picke(ii);
#pragma unroll
        for (int t = 0; t < 4; ++t) acc2[t] += w0 * (float)v0[t];
      }
    }
    float ldiv = hl == 0 ? l[0] : (hl == 1 ? l[1] : (hl == 2 ? l[2] : l[3]));
#pragma unroll
    for (int t = 0; t < 4; ++t) acc2[t] /= ldiv;
  }
  // output: lane*4+t == hl*64 + d — same (h,d) mapping as the old scalar path
  bf16x4 hi4, lo4;
#pragma unroll
  for (int t = 0; t < 4; ++t) {
    float a = acc2[t];
    bf16 h8 = (bf16)a;
    hi4[t] = h8;
    lo4[t] = (bf16)(a - (float)h8);
  }
  *(bf16x4*)(aos + (size_t)bn * 512 + lane * 4) = hi4;
  *(bf16x4*)(aos + (size_t)bn * 512 + 256 + lane * 4) = lo4;
}

// ---------------------------------------------------------------------------
// fused out-projection + bias + residual + LayerNorm -> out.
// 32 rows x 256 cols per block (grid 256), BK=32, LDS dbuf, swizzle
// (r>>1)&3.  Per-row LN: 16-lane shuffle + 4-wave LDS combine.
// ---------------------------------------------------------------------------
__global__ __launch_bounds__(256) void projln_kernel(const bf16* __restrict__ A,
                                                     const bf16* __restrict__ Bw,
                                                     const float* __restrict__ x,
                                                     const float* __restrict__ bo,
                                                     const float* __restrict__ gamma,
                                                     const float* __restrict__ beta,
                                                     float* __restrict__ out) {
  __shared__ bf16 As[2 * 32 * 32];     // 4 KB
  __shared__ bf16 Bs[2 * 256 * 32];    // 32 KB
  __shared__ float rsum[32][4];
  __shared__ float rsq[32][4];
  int tid = threadIdx.x;
  int lane = tid & 63;
  int wv = tid >> 6;
  int wn = wv * 64;                    // each wave: all 32 rows x 64 cols
  int row0 = blockIdx.x * 32;

  int rt = tid >> 2;                   // B row helper 0..63
  int ra = tid >> 2;                   // A row 0..31 (tid<128)
  int gpa = (tid & 3) ^ ((ra >> 1) & 3);
  const bf16* ga0 = A + (size_t)(row0 + ra) * 512 + gpa * 8;

  int fr = lane & 15;
  int G = lane >> 4;

  f32x4 acc[2][4] = {};

  auto issue = [&](int st, int buf) {
    int aoff = ((st >> 3) << 8) | ((st & 7) << 5);  // A: ch0 h, ch1 m
    int boff = (st & 7) << 5;                       // B: h only
    if (tid < 128)
      async_cp16(ga0 + aoff, &As[buf * 1024 + tid * 8]);
#pragma unroll
    for (int q = 0; q < 4; ++q) {
      int rb = q * 64 + rt;
      int gpb = (tid & 3) ^ ((rb >> 1) & 3);
      async_cp16(Bw + (size_t)rb * 512 + gpb * 8 + boff,
                 &Bs[buf * 8192 + (q * 256 + tid) * 8]);
    }
  };

  issue(0, 0);
  for (int st = 0; st < 16; ++st) {
    int buf = st & 1;
    if (st + 1 < 16) {
      issue(st + 1, buf ^ 1);
      WAITVM(4);  // waves 2-3: exactly st retired; waves 0-1: slightly stricter
    } else {
      WAITVM(0);
    }
    __builtin_amdgcn_s_barrier();
    bf16x8 af[2], bfr[4];
#pragma unroll
    for (int mi = 0; mi < 2; ++mi) {
      int r = mi * 16 + fr;
      af[mi] = *(const bf16x8*)&As[buf * 1024 + r * 32 + ((G ^ ((r >> 1) & 3)) << 3)];
    }
#pragma unroll
    for (int nj = 0; nj < 4; ++nj) {
      int r = wn + nj * 16 + fr;
      bfr[nj] = *(const bf16x8*)&Bs[buf * 8192 + r * 32 + ((G ^ ((r >> 1) & 3)) << 3)];
    }
#pragma unroll
    for (int mi = 0; mi < 2; ++mi)
#pragma unroll
      for (int nj = 0; nj < 4; ++nj)
        acc[mi][nj] = __builtin_amdgcn_mfma_f32_16x16x32_bf16(af[mi], bfr[nj], acc[mi][nj], 0, 0, 0);
    __builtin_amdgcn_s_barrier();
  }

  int er = (lane >> 4) * 4;
  int ec = lane & 15;
  float bo_c[4], ga_c[4], be_c[4];
#pragma unroll
  for (int nj = 0; nj < 4; ++nj) {
    int c = wn + nj * 16 + ec;
    bo_c[nj] = bo[c]; ga_c[nj] = gamma[c]; be_c[nj] = beta[c];
  }
#pragma unroll
  for (int mi = 0; mi < 2; ++mi)
#pragma unroll
    for (int reg = 0; reg < 4; ++reg) {
      int rloc = mi * 16 + er + reg;
      const float* xr = x + (size_t)(row0 + rloc) * D;
      float su = 0.f, s2 = 0.f;
#pragma unroll
      for (int nj = 0; nj < 4; ++nj) {
        float u = acc[mi][nj][reg] + bo_c[nj] + xr[wn + nj * 16 + ec];
        su += u; s2 += u * u;
      }
#pragma unroll
      for (int m = 1; m <= 8; m <<= 1) {
        su += __shfl_xor(su, m);
        s2 += __shfl_xor(s2, m);
      }
      if (ec == 0) { rsum[rloc][wv] = su; rsq[rloc][wv] = s2; }
    }
  __syncthreads();
#pragma unroll
  for (int mi = 0; mi < 2; ++mi)
#pragma unroll
    for (int reg = 0; reg < 4; ++reg) {
      int rloc = mi * 16 + er + reg;
      float s = rsum[rloc][0] + rsum[rloc][1] + rsum[rloc][2] + rsum[rloc][3];
      float q2 = rsq[rloc][0] + rsq[rloc][1] + rsq[rloc][2] + rsq[rloc][3];
      float mean = s * (1.0f / D);
      float var = q2 * (1.0f / D) - mean * mean;
      float rstd = rsqrtf(var + 1e-5f);
      const float* xr = x + (size_t)(row0 + rloc) * D;
      float* orow = out + (size_t)(row0 + rloc) * D;
#pragma unroll
      for (int nj = 0; nj < 4; ++nj) {
        float u = acc[mi][nj][reg] + bo_c[nj] + xr[wn + nj * 16 + ec];
        orow[wn + nj * 16 + ec] = (u - mean) * rstd * ga_c[nj] + be_c[nj];
      }
    }
}

// ---------------------------------------------------------------------------
// Workspace.  Common: XsN [0,8.39M) | sim [12.58M,79.69M) | norms@79.69M
//                     mask@79.99M | Wt@82.08M (ends 83,132,416)
// BIG (ws >= 125 MB): qkv(bf16)@83.13M | aos@95.72M
// SMALL: qkv@12.58M, aos@37.75M (dead-sim region, written after topk)
// ---------------------------------------------------------------------------
extern "C" void kernel_launch(void* const* d_in, const int* in_sizes, int n_in,
                              void* d_out, int out_size, void* d_ws, size_t ws_size,
                              hipStream_t stream) {
  const float* x     = (const float*)d_in[0];
  const float* Wq    = (const float*)d_in[1];
  const float* Wk    = (const float*)d_in[2];
  const float* Wv    = (const float*)d_in[3];
  const float* Wo    = (const float*)d_in[4];
  const float* bo    = (const float*)d_in[5];
  const float* gamma = (const float*)d_in[6];
  const float* beta  = (const float*)d_in[7];
  float* out = (float*)d_out;

  char* ws = (char*)d_ws;
  bf16* XsN      = (bf16*)(ws);
  float* sim     = (float*)(ws + 12582912);
  float* norms   = (float*)(ws + 79691776);
  unsigned* mask = (unsigned*)(ws + 79986688);
  bf16* Wt       = (bf16*)(ws + 82083840);

  bool big = ws_size >= (size_t)125000000;
  bf16* qkv = (bf16*)(ws + (big ? 83132416 : 12582912));
  bf16* aos = (bf16*)(ws + (big ? 95715328 : 37748736));

  const int AMAP_SIM = PK6(0, 0, 1, 0, 0, 0);  // hh + hm + mh
  const int BMAP_SIM = PK6(0, 1, 0, 0, 0, 0);
  const int AMAP_2T  = PK3(0, 1, 0);           // (h+m)_A · h_B
  const int BMAP_2T  = PK3(0, 0, 1);

  prep_kernel<<<8384, 64, 0, stream>>>(x, Wq, Wk, Wv, Wo, XsN, Wt, norms,
                                       (uint4*)mask);

  if (big) {
    gemm_fused128x256_kernel<<<480, 256, 0, stream>>>(
        XsN, sim, AMAP_SIM, BMAP_SIM, Wt, qkv, AMAP_2T, BMAP_2T, norms);
    topk_adj_kernel<<<BATCH * N, 64, 0, stream>>>(sim, mask);
  } else {
    gemm_sim_kernel<<<544, 256, 0, stream>>>(XsN, sim, AMAP_SIM, BMAP_SIM);
    topk_adj_kernel<<<BATCH * N, 64, 0, stream>>>(sim, mask);
    gemm_qkv_kernel<<<dim3(6, 64), 256, 0, stream>>>(XsN, Wt, qkv,
                                                     AMAP_2T, BMAP_2T, norms);
  }

  attn_kernel<<<(BATCH * N) / 4, 256, 0, stream>>>(qkv, mask, aos);

  projln_kernel<<<256, 256, 0, stream>>>(aos, Wt + (size_t)768 * 512,
                                         x, bo, gamma, beta, out);
}